// Round 3
// baseline (281.750 us; speedup 1.0000x reference)
//
#include <hip/hip_runtime.h>
#include <math.h>

#define BB 32
#define FF 256
#define N1 64
#define N2 256

typedef _Float16 f16;
typedef _Float16 f16x4 __attribute__((ext_vector_type(4)));
typedef _Float16 f16x8 __attribute__((ext_vector_type(8)));
typedef float f32x4 __attribute__((ext_vector_type(4)));

// ---- ws byte offsets ----
#define OFFB_W1T  0u          // 260*256*4
#define OFFB_INVT 266240u
#define OFFB_INVS 274432u
#define OFFB_SIM  307200u     // 32*64*256*4
#define OFFB_C1   2404352u    // 32*64*256*4
#define OFFB_W2H  4501504u    // 256*256*2
#define OFFB_W3H  4632576u
#define OFFB_W4H  4763648u
#define OFFB_W5H  4894720u

// W1 transpose to [c][o] f32.
__global__ void k_prep_w1t(const float* __restrict__ W1, float* __restrict__ w1t) {
  int c = blockIdx.x, o = threadIdx.x;
  w1t[c * 256 + o] = W1[o * 260 + c];
}

// f16 copies of W2..W5 (row-major [o][k]).
__global__ void k_half(const float* __restrict__ W2, const float* __restrict__ W3,
                       const float* __restrict__ W4, const float* __restrict__ W5,
                       f16* __restrict__ w2h, f16* __restrict__ w3h,
                       f16* __restrict__ w4h, f16* __restrict__ w5h) {
  int o = blockIdx.x, m = blockIdx.y, k = threadIdx.x;
  int idx = o * 256 + k;
  if (m == 0)      w2h[idx] = (f16)W2[idx];
  else if (m == 1) w3h[idx] = (f16)W3[idx];
  else if (m == 2) w4h[idx] = (f16)W4[idx];
  else             w5h[idx] = (f16)W5[idx];
}

__global__ void k_norms(const float* __restrict__ s, const float* __restrict__ t,
                        float* __restrict__ invt, float* __restrict__ invs) {
  int b = blockIdx.x, tid = threadIdx.x;
  {
    const float* sp = s + b * FF * N2 + tid;
    float acc = 0.f;
#pragma unroll 4
    for (int f = 0; f < FF; ++f) { float v = sp[f * N2]; acc = fmaf(v, v, acc); }
    invs[b * N2 + tid] = 1.0f / fmaxf(sqrtf(acc), 1e-8f);
  }
  if (tid < N1) {
    const float* tp = t + b * FF * N1 + tid;
    float acc = 0.f;
#pragma unroll 4
    for (int f = 0; f < FF; ++f) { float v = tp[f * N1]; acc = fmaf(v, v, acc); }
    invt[b * N1 + tid] = 1.0f / fmaxf(sqrtf(acc), 1e-8f);
  }
}

__global__ void k_sim(const float* __restrict__ t, const float* __restrict__ s,
                      const float* __restrict__ invt, const float* __restrict__ invs,
                      float* __restrict__ sim) {
  int n = blockIdx.x, b = blockIdx.y, m = threadIdx.x;
  __shared__ float tl[FF];
  tl[m] = t[(b * FF + m) * N1 + n];
  __syncthreads();
  const float* sp = s + b * FF * N2 + m;
  float acc = 0.f;
#pragma unroll 4
  for (int f = 0; f < FF; ++f) acc = fmaf(tl[f], sp[f * N2], acc);
  sim[(b * N1 + n) * N2 + m] = acc * invt[b * N1 + n] * invs[b * N2 + m];
}

__global__ void k_c1(const float* __restrict__ t, const float* __restrict__ seeds,
                     const float* __restrict__ b1, const float* __restrict__ w1t,
                     float* __restrict__ c1) {
  int n = blockIdx.x, b = blockIdx.y, o = threadIdx.x;
  __shared__ float tl[FF];
  tl[o] = t[(b * FF + o) * N1 + n];
  __syncthreads();
  float s0 = seeds[(b * N1 + n) * 3 + 0];
  float s1 = seeds[(b * N1 + n) * 3 + 1];
  float s2 = seeds[(b * N1 + n) * 3 + 2];
  float acc = b1[o];
  acc = fmaf(w1t[1 * 256 + o], s0, acc);
  acc = fmaf(w1t[2 * 256 + o], s1, acc);
  acc = fmaf(w1t[3 * 256 + o], s2, acc);
#pragma unroll 4
  for (int k = 0; k < FF; ++k) acc = fmaf(w1t[(4 + k) * 256 + o], tl[k], acc);
  c1[(b * N1 + n) * 256 + o] = acc;
}

// ---------------------------------------------------------------------------
// Fragment-ordered LDS layout for a 32m x 256k f16 tile:
//   element (m, k): r=m&15, mf=m>>4, ks=k>>5, g=(k>>3)&3, e=k&7
//   byte = (ks*2+mf)*1024 + (g*16+r)*16 + e*2
// GEMM read of frag (ks,mf): lane L at byte (ks*2+mf)*1024 + L*16  (stride-1).
// ---------------------------------------------------------------------------

#define ZERO_ACC                                                  \
  _Pragma("unroll") for (int of = 0; of < 4; ++of)                \
  _Pragma("unroll") for (int mf = 0; mf < 2; ++mf)                \
      acc[of][mf] = (f32x4){0.f, 0.f, 0.f, 0.f};

#define GEMM4(SRC, WREG)                                                        \
  _Pragma("unroll") for (int ks = 0; ks < 8; ++ks)                              \
  _Pragma("unroll") for (int mf = 0; mf < 2; ++mf) {                            \
    f16x8 bf = *(const f16x8*)((SRC) + (ks * 2 + mf) * 1024 + lane * 16);       \
    _Pragma("unroll") for (int of = 0; of < 4; ++of)                            \
      acc[of][mf] = __builtin_amdgcn_mfma_f32_16x16x32_f16(WREG[of][ks], bf,    \
                                                           acc[of][mf], 0, 0, 0); \
  }

// store acc (+bias, relu) into fragment-ordered tile DST (k = this layer's o)
#define STORE_FRAG(DST, BIAS, RELU)                                             \
  _Pragma("unroll") for (int of = 0; of < 4; ++of)                              \
  _Pragma("unroll") for (int mf = 0; mf < 2; ++mf) {                            \
    f16x4 hv;                                                                   \
    _Pragma("unroll") for (int j = 0; j < 4; ++j) {                             \
      float v = acc[of][mf][j] + BIAS[of][j];                                   \
      hv[j] = (f16)(RELU ? fmaxf(v, 0.f) : v);                                  \
    }                                                                           \
    *(f16x4*)((DST) + ((2 * w + (of >> 1)) * 2 + mf) * 1024 +                   \
              (((of * 2) + (g >> 1)) & 3) * 256 + r * 16 + (g & 1) * 8) = hv;   \
  }

// layer-1 producer: thread (w,lane) writes subtiles s=j*4+w at slot lane*16
#define PRODUCE_Y1(NN, DST)                                                     \
  {                                                                             \
    float simv = sml[(NN) * 32 + mfw * 16 + r];                                 \
    const float* c1row = c1l + (NN) * 256;                                      \
    _Pragma("unroll") for (int j = 0; j < 4; ++j) {                             \
      int kb = (2 * j + a2) * 32 + g * 8;                                       \
      f32x4 ca = *(const f32x4*)(c1row + kb);                                   \
      f32x4 cb = *(const f32x4*)(c1row + kb + 4);                               \
      f16x8 h;                                                                  \
      _Pragma("unroll") for (int q = 0; q < 4; ++q) {                           \
        h[q] = (f16)fmaxf(fmaf(w1a[j][q], simv, ca[q]), 0.f);                   \
        h[4 + q] = (f16)fmaxf(fmaf(w1b[j][q], simv, cb[q]), 0.f);               \
      }                                                                         \
      *(f16x8*)((DST) + (j * 4 + w) * 1024 + lane * 16) = h;                    \
    }                                                                           \
  }

// Fused L1-3 + maxpool + L4-5. Grid (8 mtiles, 32 b), 256 thr = 4 waves.
// Wave w owns o-range [64w, 64w+64); W frags register/AGPR-resident.
__global__ __launch_bounds__(256, 1) void k_fused(
    const float* __restrict__ b2, const float* __restrict__ b3,
    const float* __restrict__ b4, const float* __restrict__ b5,
    const float* __restrict__ sim, const float* __restrict__ c1,
    const f16* __restrict__ w2h, const f16* __restrict__ w3h,
    const f16* __restrict__ w4h, const f16* __restrict__ w5h,
    const float* __restrict__ w1t, float* __restrict__ out) {
  const int mt = blockIdx.x, b = blockIdx.y;
  const int mb = mt * 32;
  const int tid = threadIdx.x;
  const int w = tid >> 6, lane = tid & 63;
  const int g = lane >> 4, r = lane & 15;
  const int obase = w * 64;
  const int a2 = w >> 1, mfw = w & 1;

  __shared__ __align__(16) char y1l[2 * 16384];
  __shared__ __align__(16) char y2l[16384];
  __shared__ __align__(16) float c1l[64 * 256];
  __shared__ __align__(16) float sml[64 * 32];

  // ---- stage c1 (64 KB) + sim (8 KB) tiles into LDS
  {
    const float* c1g = c1 + (size_t)(b * N1) * 256;
#pragma unroll
    for (int i = 0; i < 16; ++i) {
      int off = i * 1024 + tid * 4;
      *(f32x4*)(c1l + off) = *(const f32x4*)(c1g + off);
    }
    const float* simg = sim + (size_t)(b * N1) * N2 + mb;
    int n = tid >> 2, mo = (tid & 3) * 8;
    *(f32x4*)(sml + n * 32 + mo) = *(const f32x4*)(simg + n * N2 + mo);
    *(f32x4*)(sml + n * 32 + mo + 4) = *(const f32x4*)(simg + n * N2 + mo + 4);
  }

  // ---- W2/W3 fragments -> registers (4 of x 8 ks each)
  f16x8 wA[4][8], wB[4][8];
#pragma unroll
  for (int of = 0; of < 4; ++of)
#pragma unroll
    for (int ks = 0; ks < 8; ++ks) {
      int row = obase + of * 16 + r;
      int col = ks * 32 + g * 8;
      wA[of][ks] = *(const f16x8*)(w2h + row * 256 + col);
      wB[of][ks] = *(const f16x8*)(w3h + row * 256 + col);
    }
  f32x4 bias2[4], bias3[4];
#pragma unroll
  for (int of = 0; of < 4; ++of) {
    bias2[of] = *(const f32x4*)(b2 + obase + of * 16 + g * 4);
    bias3[of] = *(const f32x4*)(b3 + obase + of * 16 + g * 4);
  }
  // W1 col-0 chunks for the producer (loop-invariant, register-resident)
  f32x4 w1a[4], w1b[4];
#pragma unroll
  for (int j = 0; j < 4; ++j) {
    int kb = (2 * j + a2) * 32 + g * 8;
    w1a[j] = *(const f32x4*)(w1t + kb);
    w1b[j] = *(const f32x4*)(w1t + kb + 4);
  }

  f32x4 pool[4][2];
#pragma unroll
  for (int of = 0; of < 4; ++of)
#pragma unroll
    for (int mf = 0; mf < 2; ++mf) pool[of][mf] = (f32x4){0.f, 0.f, 0.f, 0.f};
  f32x4 acc[4][2];

  __syncthreads();           // c1l/sml published
  PRODUCE_Y1(0, y1l);        // prologue fill of buf0
  int cur = 0;

  for (int n = 0; n < N1; ++n) {
    __syncthreads();         // publish y1[cur]; y2 readers of prev iter done
    char* ycur = y1l + cur * 16384;
    // phase A: layer 2
    ZERO_ACC;
    GEMM4(ycur, wA);
    STORE_FRAG(y2l, bias2, 1);
    __syncthreads();         // publish y2
    // phase B: layer 3 + pool; pipeline layer-1 of n+1 into other y1 buf
    ZERO_ACC;
    GEMM4(y2l, wB);
    if (n + 1 < N1) { PRODUCE_Y1(n + 1, y1l + (cur ^ 1) * 16384); }
#pragma unroll
    for (int of = 0; of < 4; ++of)
#pragma unroll
      for (int mf = 0; mf < 2; ++mf)
#pragma unroll
        for (int j = 0; j < 4; ++j)
          pool[of][mf][j] = fmaxf(pool[of][mf][j],
                                  fmaxf(acc[of][mf][j] + bias3[of][j], 0.f));
    cur ^= 1;
  }

  // ---- tail: pooled tile -> y1 buf0 as layer-4 input
#pragma unroll
  for (int of = 0; of < 4; ++of)
#pragma unroll
    for (int mf = 0; mf < 2; ++mf) {
      f16x4 hv;
#pragma unroll
      for (int j = 0; j < 4; ++j) hv[j] = (f16)pool[of][mf][j];
      *(f16x4*)(y1l + ((2 * w + (of >> 1)) * 2 + mf) * 1024 +
                (((of * 2) + (g >> 1)) & 3) * 256 + r * 16 + (g & 1) * 8) = hv;
    }
  // swap W4/W5 + biases into the same registers
#pragma unroll
  for (int of = 0; of < 4; ++of) {
#pragma unroll
    for (int ks = 0; ks < 8; ++ks) {
      int row = obase + of * 16 + r;
      int col = ks * 32 + g * 8;
      wA[of][ks] = *(const f16x8*)(w4h + row * 256 + col);
      wB[of][ks] = *(const f16x8*)(w5h + row * 256 + col);
    }
    bias2[of] = *(const f32x4*)(b4 + obase + of * 16 + g * 4);
    bias3[of] = *(const f32x4*)(b5 + obase + of * 16 + g * 4);
  }
  __syncthreads();           // pooled published; all y2 reads done
  // layer 4
  ZERO_ACC;
  GEMM4(y1l, wA);
  STORE_FRAG(y2l, bias2, 1);
  __syncthreads();
  // layer 5 (no relu) -> out f32 [b][o][m]
  ZERO_ACC;
  GEMM4(y2l, wB);
#pragma unroll
  for (int of = 0; of < 4; ++of)
#pragma unroll
    for (int mf = 0; mf < 2; ++mf) {
      float* op = out + ((size_t)(b * 256 + obase + of * 16 + g * 4)) * 256 +
                  mb + mf * 16 + r;
#pragma unroll
      for (int j = 0; j < 4; ++j) op[(size_t)j * 256] = acc[of][mf][j] + bias3[of][j];
    }
}

extern "C" void kernel_launch(void* const* d_in, const int* in_sizes, int n_in,
                              void* d_out, int out_size, void* d_ws, size_t ws_size,
                              hipStream_t stream) {
  const float* sf = (const float*)d_in[0];
  const float* tf = (const float*)d_in[1];
  const float* seeds = (const float*)d_in[2];
  const float* W1 = (const float*)d_in[3];
  const float* b1 = (const float*)d_in[4];
  const float* W2 = (const float*)d_in[5];
  const float* b2 = (const float*)d_in[6];
  const float* W3 = (const float*)d_in[7];
  const float* b3 = (const float*)d_in[8];
  const float* W4 = (const float*)d_in[9];
  const float* b4 = (const float*)d_in[10];
  const float* W5 = (const float*)d_in[11];
  const float* b5 = (const float*)d_in[12];
  char* wsb = (char*)d_ws;
  float* w1t = (float*)(wsb + OFFB_W1T);
  float* invt = (float*)(wsb + OFFB_INVT);
  float* invs = (float*)(wsb + OFFB_INVS);
  float* sim = (float*)(wsb + OFFB_SIM);
  float* c1 = (float*)(wsb + OFFB_C1);
  f16* w2h = (f16*)(wsb + OFFB_W2H);
  f16* w3h = (f16*)(wsb + OFFB_W3H);
  f16* w4h = (f16*)(wsb + OFFB_W4H);
  f16* w5h = (f16*)(wsb + OFFB_W5H);
  float* out = (float*)d_out;

  k_prep_w1t<<<dim3(260), 256, 0, stream>>>(W1, w1t);
  k_half<<<dim3(256, 4), 256, 0, stream>>>(W2, W3, W4, W5, w2h, w3h, w4h, w5h);
  k_norms<<<dim3(BB), 256, 0, stream>>>(sf, tf, invt, invs);
  k_sim<<<dim3(N1, BB), 256, 0, stream>>>(tf, sf, invt, invs, sim);
  k_c1<<<dim3(N1, BB), 256, 0, stream>>>(tf, seeds, b1, w1t, c1);
  k_fused<<<dim3(8, BB), 256, 0, stream>>>(b2, b3, b4, b5, sim, c1,
                                           w2h, w3h, w4h, w5h, w1t, out);
}

// Round 4
// 181.918 us; speedup vs baseline: 1.5488x; 1.5488x over previous
//
#include <hip/hip_runtime.h>
#include <math.h>

#define BB 32
#define FF 256
#define N1 64
#define N2 256

typedef _Float16 f16;
typedef _Float16 f16x4 __attribute__((ext_vector_type(4)));
typedef _Float16 f16x8 __attribute__((ext_vector_type(8)));
typedef float f32x4 __attribute__((ext_vector_type(4)));

// ---- ws byte offsets ----
#define OFFB_W14T 0u        // 4*256 f32  (W1 cols 0..3, [c][o])
#define OFFB_INVT 4096u     // 32*64 f32
#define OFFB_INVS 12288u    // 32*256 f32
#define OFFB_W1H  45056u    // 256*256 f16 (W1 cols 4..259, [o][k])
#define OFFB_W2H  176128u   // 256*256 f16 each
#define OFFB_W3H  307200u
#define OFFB_W4H  438272u
#define OFFB_W5H  569344u   // end 700416

__global__ void k_prep(const float* __restrict__ W1, const float* __restrict__ W2,
                       const float* __restrict__ W3, const float* __restrict__ W4,
                       const float* __restrict__ W5, char* __restrict__ wsb) {
  int x = blockIdx.x, m = blockIdx.y, t = threadIdx.x;
  int idx = x * 256 + t;
  if (m == 0)      ((f16*)(wsb + OFFB_W2H))[idx] = (f16)W2[idx];
  else if (m == 1) ((f16*)(wsb + OFFB_W3H))[idx] = (f16)W3[idx];
  else if (m == 2) ((f16*)(wsb + OFFB_W4H))[idx] = (f16)W4[idx];
  else if (m == 3) ((f16*)(wsb + OFFB_W5H))[idx] = (f16)W5[idx];
  else if (m == 4) ((f16*)(wsb + OFFB_W1H))[idx] = (f16)W1[x * 260 + 4 + t];
  else if (x < 4)  ((float*)(wsb + OFFB_W14T))[x * 256 + t] = W1[t * 260 + x];
}

__global__ void k_norms(const float* __restrict__ s, const float* __restrict__ t,
                        char* __restrict__ wsb) {
  int b = blockIdx.x, tid = threadIdx.x;
  float* invt = (float*)(wsb + OFFB_INVT);
  float* invs = (float*)(wsb + OFFB_INVS);
  {
    const float* sp = s + b * FF * N2 + tid;
    float acc = 0.f;
#pragma unroll 4
    for (int f = 0; f < FF; ++f) { float v = sp[f * N2]; acc = fmaf(v, v, acc); }
    invs[b * N2 + tid] = 1.0f / fmaxf(sqrtf(acc), 1e-8f);
  }
  if (tid < N1) {
    const float* tp = t + b * FF * N1 + tid;
    float acc = 0.f;
#pragma unroll 4
    for (int f = 0; f < FF; ++f) { float v = tp[f * N1]; acc = fmaf(v, v, acc); }
    invt[b * N1 + tid] = 1.0f / fmaxf(sqrtf(acc), 1e-8f);
  }
}

// ---------------------------------------------------------------------------
// Fragment-ordered LDS layout for a 32m x 256k f16 tile (verified R3):
//   element (m,k): byte = ((k>>5)*2 + (m>>4))*1024 + (((k>>3)&3)*16 + (m&15))*16 + (k&7)*2
// GEMM read of frag: base + lane*16 (stride-1, conflict-free).
// t-tile (64n x 256f): byte = ((f>>5)*4 + (n>>4))*1024 + ((f>>3&3)*16 + (n&15))*16 + (f&7)*2
// ---------------------------------------------------------------------------

#define ZERO_ACC                                                  \
  _Pragma("unroll") for (int of = 0; of < 4; ++of)                \
  _Pragma("unroll") for (int mf = 0; mf < 2; ++mf)                \
      acc[of][mf] = (f32x4){0.f, 0.f, 0.f, 0.f};

#define GEMM4(SRC)                                                                \
  _Pragma("unroll") for (int ks = 0; ks < 8; ++ks)                                \
  _Pragma("unroll") for (int mf = 0; mf < 2; ++mf) {                              \
    f16x8 bf = *(const f16x8*)((SRC) + (ks * 2 + mf) * 1024 + lane * 16);         \
    _Pragma("unroll") for (int of = 0; of < 4; ++of)                              \
      acc[of][mf] = __builtin_amdgcn_mfma_f32_16x16x32_f16(wreg[of][ks], bf,      \
                                                           acc[of][mf], 0, 0, 0); \
  }

// bias+relu+cvt, store acc into fragment-ordered tile (k-dim = o-range of wg)
#define STORE_FRAG(DST)                                                           \
  _Pragma("unroll") for (int of = 0; of < 4; ++of)                                \
  _Pragma("unroll") for (int mf = 0; mf < 2; ++mf) {                              \
    f16x4 hv;                                                                     \
    _Pragma("unroll") for (int j = 0; j < 4; ++j)                                 \
        hv[j] = (f16)fmaxf(acc[of][mf][j] + biasv[of][j], 0.f);                   \
    *(f16x4*)((DST) + ((2 * wg + (of >> 1)) * 2 + mf) * 1024 +                    \
              (((of * 2) + (g >> 1)) & 3) * 256 + r * 16 + (g & 1) * 8) = hv;     \
  }

#define POOLUP                                                                    \
  _Pragma("unroll") for (int of = 0; of < 4; ++of)                                \
  _Pragma("unroll") for (int mf = 0; mf < 2; ++mf)                                \
  _Pragma("unroll") for (int j = 0; j < 4; ++j) {                                 \
    f16 hv = (f16)fmaxf(acc[of][mf][j] + biasv[of][j], 0.f);                      \
    if (hv > pool[of][mf][j]) pool[of][mf][j] = hv;                               \
  }

// layer-1 producer (B-group): thread (wg,lane) writes subtiles j*4+wg
#define PRODUCE_Y1(NN, DST)                                                       \
  {                                                                               \
    float simv = sml[(NN) * 32 + mfw * 16 + r];                                   \
    const float* c1row = c1l + (NN) * 260;                                        \
    _Pragma("unroll") for (int j = 0; j < 4; ++j) {                               \
      int kb = (2 * j + a2) * 32 + g * 8;                                         \
      f32x4 ca = *(const f32x4*)(c1row + kb);                                     \
      f32x4 cb = *(const f32x4*)(c1row + kb + 4);                                 \
      f16x8 h;                                                                    \
      _Pragma("unroll") for (int q = 0; q < 4; ++q) {                             \
        h[q] = (f16)fmaxf(fmaf(w1a[j][q], simv, ca[q]), 0.f);                     \
        h[4 + q] = (f16)fmaxf(fmaf(w1b[j][q], simv, cb[q]), 0.f);                 \
      }                                                                           \
      *(f16x8*)((DST) + (j * 4 + wg) * 1024 + lane * 16) = h;                     \
    }                                                                             \
  }

// Mega: stage t/s -> sim-GEMM + c1-GEMM -> {L1 produce | L2 | L3+pool} pipeline
// -> L4 -> L5. Grid (8 mtiles, 32 b), 512 thr = 8 waves (A=0-3: L2; B=4-7: L3).
__global__ __launch_bounds__(512, 2) void k_mega(
    const float* __restrict__ sf, const float* __restrict__ tf,
    const float* __restrict__ seeds, const float* __restrict__ b1,
    const float* __restrict__ b2, const float* __restrict__ b3,
    const float* __restrict__ b4, const float* __restrict__ b5,
    const char* __restrict__ wsb, float* __restrict__ out) {
  const int mt = blockIdx.x, b = blockIdx.y, mb = mt * 32;
  const int tid = threadIdx.x;
  const int w = tid >> 6, lane = tid & 63, g = lane >> 4, r = lane & 15;
  const int grp = w >> 2, wg = w & 3;
  const int a2 = wg >> 1, mfw = wg & 1;

  const float* w14t = (const float*)(wsb + OFFB_W14T);
  const float* invt = (const float*)(wsb + OFFB_INVT) + b * 64;
  const float* invs = (const float*)(wsb + OFFB_INVS) + b * 256;
  const f16* w1h = (const f16*)(wsb + OFFB_W1H);
  const f16* w2h = (const f16*)(wsb + OFFB_W2H);
  const f16* w3h = (const f16*)(wsb + OFFB_W3H);
  const f16* w4h = (const f16*)(wsb + OFFB_W4H);
  const f16* w5h = (const f16*)(wsb + OFFB_W5H);

  __shared__ __align__(16) char y1l[2 * 16384];
  __shared__ __align__(16) char y2l[2 * 16384];   // pre-loop: t-tile staging
  __shared__ __align__(16) float c1l[64 * 260];
  __shared__ __align__(16) float sml[64 * 32];

  // ---- stage raw t (64n x 256f f16, frag order) into y2l region
  {
    int n = tid & 63, fb = tid >> 6;
#pragma unroll
    for (int j = 0; j < 4; ++j) {
      int foct = j * 8 + fb;
      f16x8 h;
#pragma unroll
      for (int e = 0; e < 8; ++e)
        h[e] = (f16)tf[((size_t)b * FF + foct * 8 + e) * N1 + n];
      *(f16x8*)(y2l + ((foct >> 2) * 4 + (n >> 4)) * 1024 +
                ((foct & 3) * 16 + (n & 15)) * 16) = h;
    }
  }
  // ---- stage s_norm (32m x 256f f16, frag order) into y1l buf0
  {
    int m = tid & 31, q = tid >> 5;
    float iv = invs[mb + m];
#pragma unroll
    for (int j = 0; j < 2; ++j) {
      int foct = j * 16 + q;
      f16x8 h;
#pragma unroll
      for (int e = 0; e < 8; ++e)
        h[e] = (f16)(sf[((size_t)b * FF + foct * 8 + e) * N2 + mb + m] * iv);
      *(f16x8*)(y1l + ((foct >> 2) * 2 + (m >> 4)) * 1024 +
                ((foct & 3) * 16 + (m & 15)) * 16) = h;
    }
  }
  __syncthreads();

  // ---- sim-GEMM (A-group): sim[n,m] = (t^T s_norm)*invt -> sml
  if (grp == 0) {
    f32x4 sa[2] = {{0.f, 0.f, 0.f, 0.f}, {0.f, 0.f, 0.f, 0.f}};
#pragma unroll
    for (int ks = 0; ks < 8; ++ks) {
      f16x8 af = *(const f16x8*)(y2l + (ks * 4 + wg) * 1024 + lane * 16);
#pragma unroll
      for (int mf = 0; mf < 2; ++mf) {
        f16x8 bf = *(const f16x8*)(y1l + (ks * 2 + mf) * 1024 + lane * 16);
        sa[mf] = __builtin_amdgcn_mfma_f32_16x16x32_f16(af, bf, sa[mf], 0, 0, 0);
      }
    }
    float itv[4];
#pragma unroll
    for (int j = 0; j < 4; ++j) itv[j] = invt[wg * 16 + 4 * g + j];
#pragma unroll
    for (int mf = 0; mf < 2; ++mf)
#pragma unroll
      for (int j = 0; j < 4; ++j)
        sml[(wg * 16 + 4 * g + j) * 32 + mf * 16 + r] = sa[mf][j] * itv[j];
  }

  // ---- c1-GEMM (all 8 waves, o-split 32): c1[n,o] -> c1l (+bias +seeds)
  {
    f16x8 w1f[2][8];
#pragma unroll
    for (int ofl = 0; ofl < 2; ++ofl)
#pragma unroll
      for (int ks = 0; ks < 8; ++ks)
        w1f[ofl][ks] = *(const f16x8*)(w1h + (w * 32 + ofl * 16 + r) * 256 +
                                       ks * 32 + g * 8);
    f32x4 ac[2][4];
#pragma unroll
    for (int ofl = 0; ofl < 2; ++ofl)
#pragma unroll
      for (int nf = 0; nf < 4; ++nf) ac[ofl][nf] = (f32x4){0.f, 0.f, 0.f, 0.f};
#pragma unroll
    for (int ks = 0; ks < 8; ++ks)
#pragma unroll
      for (int nf = 0; nf < 4; ++nf) {
        f16x8 bf = *(const f16x8*)(y2l + (ks * 4 + nf) * 1024 + lane * 16);
        ac[0][nf] = __builtin_amdgcn_mfma_f32_16x16x32_f16(w1f[0][ks], bf,
                                                           ac[0][nf], 0, 0, 0);
        ac[1][nf] = __builtin_amdgcn_mfma_f32_16x16x32_f16(w1f[1][ks], bf,
                                                           ac[1][nf], 0, 0, 0);
      }
#pragma unroll
    for (int nf = 0; nf < 4; ++nf) {
      int n = nf * 16 + r;
      const float* sd = seeds + ((size_t)b * 64 + n) * 3;
      float sx = sd[0], sy = sd[1], sz = sd[2];
#pragma unroll
      for (int ofl = 0; ofl < 2; ++ofl)
#pragma unroll
        for (int j = 0; j < 4; ++j) {
          int o = w * 32 + ofl * 16 + 4 * g + j;
          c1l[n * 260 + o] = ac[ofl][nf][j] + b1[o] + w14t[256 + o] * sx +
                             w14t[512 + o] * sy + w14t[768 + o] * sz;
        }
    }
  }
  __syncthreads();   // c1l, sml published; staging reads done

  // ---- persistent registers (same names both groups -> shared allocation)
  f16x8 wreg[4][8];
  f32x4 biasv[4];
  f32x4 w1a[4], w1b[4];
  f16x4 pool[4][2];
  f32x4 acc[4][2];
  {
    const f16* wsrc = grp ? w3h : w2h;
    const float* bsrc = grp ? b3 : b2;
#pragma unroll
    for (int of = 0; of < 4; ++of) {
#pragma unroll
      for (int ks = 0; ks < 8; ++ks)
        wreg[of][ks] = *(const f16x8*)(wsrc + (wg * 64 + of * 16 + r) * 256 +
                                       ks * 32 + g * 8);
      biasv[of] = *(const f32x4*)(bsrc + wg * 64 + of * 16 + g * 4);
    }
  }
#pragma unroll
  for (int of = 0; of < 4; ++of)
#pragma unroll
    for (int mf = 0; mf < 2; ++mf) pool[of][mf] = (f16x4){0, 0, 0, 0};
  if (grp == 1) {
#pragma unroll
    for (int j = 0; j < 4; ++j) {
      int kb = (2 * j + a2) * 32 + g * 8;
      w1a[j] = *(const f32x4*)(w14t + kb);
      w1b[j] = *(const f32x4*)(w14t + kb + 4);
    }
    PRODUCE_Y1(0, y1l);   // overwrites s-stage (reads done pre-barrier)
  }
  __syncthreads();        // y1[0] published

  // ---- main pipeline: A: L2(n)->y2[n&1]; B: L3(n-1)+pool, produce y1[n+1]
  for (int n = 0; n < N1; ++n) {
    if (grp == 0) {
      ZERO_ACC;
      GEMM4(y1l + (n & 1) * 16384);
      STORE_FRAG(y2l + (n & 1) * 16384);
    } else {
      if (n > 0) {
        ZERO_ACC;
        GEMM4(y2l + ((n - 1) & 1) * 16384);
        POOLUP;
      }
      if (n + 1 < N1) PRODUCE_Y1(n + 1, y1l + ((n + 1) & 1) * 16384);
    }
    __syncthreads();
  }

  // ---- tail: B finishes L3(63), stores pooled tile; A loads W4
  if (grp == 1) {
    ZERO_ACC;
    GEMM4(y2l + 16384);
    POOLUP;
#pragma unroll
    for (int of = 0; of < 4; ++of)
#pragma unroll
      for (int mf = 0; mf < 2; ++mf)
        *(f16x4*)(y1l + ((2 * wg + (of >> 1)) * 2 + mf) * 1024 +
                  (((of * 2) + (g >> 1)) & 3) * 256 + r * 16 + (g & 1) * 8) =
            pool[of][mf];
  } else {
#pragma unroll
    for (int of = 0; of < 4; ++of) {
#pragma unroll
      for (int ks = 0; ks < 8; ++ks)
        wreg[of][ks] = *(const f16x8*)(w4h + (wg * 64 + of * 16 + r) * 256 +
                                       ks * 32 + g * 8);
      biasv[of] = *(const f32x4*)(b4 + wg * 64 + of * 16 + g * 4);
    }
  }
  __syncthreads();
  // ---- L4 (A-group); B loads W5
  if (grp == 0) {
    ZERO_ACC;
    GEMM4(y1l);
    STORE_FRAG(y2l);
  } else {
#pragma unroll
    for (int of = 0; of < 4; ++of) {
#pragma unroll
      for (int ks = 0; ks < 8; ++ks)
        wreg[of][ks] = *(const f16x8*)(w5h + (wg * 64 + of * 16 + r) * 256 +
                                       ks * 32 + g * 8);
      biasv[of] = *(const f32x4*)(b5 + wg * 64 + of * 16 + g * 4);
    }
  }
  __syncthreads();
  // ---- L5 (B-group, no relu) -> out
  if (grp == 1) {
    ZERO_ACC;
    GEMM4(y2l);
#pragma unroll
    for (int of = 0; of < 4; ++of)
#pragma unroll
      for (int mf = 0; mf < 2; ++mf) {
        float* op = out + ((size_t)(b * 256 + wg * 64 + of * 16 + g * 4)) * 256 +
                    mb + mf * 16 + r;
#pragma unroll
        for (int j = 0; j < 4; ++j)
          op[(size_t)j * 256] = acc[of][mf][j] + biasv[of][j];
      }
  }
}

extern "C" void kernel_launch(void* const* d_in, const int* in_sizes, int n_in,
                              void* d_out, int out_size, void* d_ws, size_t ws_size,
                              hipStream_t stream) {
  const float* sf = (const float*)d_in[0];
  const float* tf = (const float*)d_in[1];
  const float* seeds = (const float*)d_in[2];
  const float* W1 = (const float*)d_in[3];
  const float* b1 = (const float*)d_in[4];
  const float* W2 = (const float*)d_in[5];
  const float* b2 = (const float*)d_in[6];
  const float* W3 = (const float*)d_in[7];
  const float* b3 = (const float*)d_in[8];
  const float* W4 = (const float*)d_in[9];
  const float* b4 = (const float*)d_in[10];
  const float* W5 = (const float*)d_in[11];
  const float* b5 = (const float*)d_in[12];
  char* wsb = (char*)d_ws;
  float* out = (float*)d_out;

  k_prep<<<dim3(256, 6), 256, 0, stream>>>(W1, W2, W3, W4, W5, wsb);
  k_norms<<<dim3(BB), 256, 0, stream>>>(sf, tf, wsb);
  k_mega<<<dim3(8, BB), 512, 0, stream>>>(sf, tf, seeds, b1, b2, b3, b4, b5,
                                          wsb, out);
}

// Round 5
// 171.076 us; speedup vs baseline: 1.6469x; 1.0634x over previous
//
#include <hip/hip_runtime.h>
#include <math.h>

#define BB 32
#define FF 256
#define N1 64
#define N2 256

typedef _Float16 f16;
typedef _Float16 f16x4 __attribute__((ext_vector_type(4)));
typedef _Float16 f16x8 __attribute__((ext_vector_type(8)));
typedef float f32x4 __attribute__((ext_vector_type(4)));

// ---- ws byte offsets ----
#define OFFB_W14T 0u        // 4*256 f32  (W1 cols 0..3, [c][o])
#define OFFB_INVT 4096u     // 32*64 f32
#define OFFB_INVS 12288u    // 32*256 f32
#define OFFB_W1H  45056u    // 256*256 f16 (W1 cols 4..259, [o][k])
#define OFFB_W2H  176128u
#define OFFB_W3H  307200u
#define OFFB_W4H  438272u
#define OFFB_W5H  569344u

__global__ void k_prep(const float* __restrict__ W1, const float* __restrict__ W2,
                       const float* __restrict__ W3, const float* __restrict__ W4,
                       const float* __restrict__ W5, char* __restrict__ wsb) {
  int x = blockIdx.x, m = blockIdx.y, t = threadIdx.x;
  int idx = x * 256 + t;
  if (m == 0)      ((f16*)(wsb + OFFB_W2H))[idx] = (f16)W2[idx];
  else if (m == 1) ((f16*)(wsb + OFFB_W3H))[idx] = (f16)W3[idx];
  else if (m == 2) ((f16*)(wsb + OFFB_W4H))[idx] = (f16)W4[idx];
  else if (m == 3) ((f16*)(wsb + OFFB_W5H))[idx] = (f16)W5[idx];
  else if (m == 4) ((f16*)(wsb + OFFB_W1H))[idx] = (f16)W1[x * 260 + 4 + t];
  else if (x < 4)  ((float*)(wsb + OFFB_W14T))[x * 256 + t] = W1[t * 260 + x];
}

__global__ void k_norms(const float* __restrict__ s, const float* __restrict__ t,
                        char* __restrict__ wsb) {
  int b = blockIdx.x, tid = threadIdx.x;
  float* invt = (float*)(wsb + OFFB_INVT);
  float* invs = (float*)(wsb + OFFB_INVS);
  {
    const float* sp = s + b * FF * N2 + tid;
    float acc = 0.f;
#pragma unroll 4
    for (int f = 0; f < FF; ++f) { float v = sp[f * N2]; acc = fmaf(v, v, acc); }
    invs[b * N2 + tid] = 1.0f / fmaxf(sqrtf(acc), 1e-8f);
  }
  if (tid < N1) {
    const float* tp = t + b * FF * N1 + tid;
    float acc = 0.f;
#pragma unroll 4
    for (int f = 0; f < FF; ++f) { float v = tp[f * N1]; acc = fmaf(v, v, acc); }
    invt[b * N1 + tid] = 1.0f / fmaxf(sqrtf(acc), 1e-8f);
  }
}

// Fragment-ordered layouts (verified R3/R4):
// 32m x 256k tile: frag(ks,mf) at (ks*2+mf)*1024, lane L at +L*16 (b128, no-conflict)
// 64n x 256f t-tile: frag((f>>5)*4 + (n>>4))*1024.

#define ZERO_ACC                                                  \
  _Pragma("unroll") for (int of = 0; of < 2; ++of)                \
  _Pragma("unroll") for (int mf = 0; mf < 2; ++mf)                \
      acc[of][mf] = (f32x4){0.f, 0.f, 0.f, 0.f};

#define GEMM2(SRC)                                                                \
  __builtin_amdgcn_s_setprio(1);                                                  \
  _Pragma("unroll") for (int ks = 0; ks < 8; ++ks)                                \
  _Pragma("unroll") for (int mf = 0; mf < 2; ++mf) {                              \
    f16x8 bf = *(const f16x8*)((SRC) + (ks * 2 + mf) * 1024 + lane * 16);         \
    _Pragma("unroll") for (int of = 0; of < 2; ++of)                              \
      acc[of][mf] = __builtin_amdgcn_mfma_f32_16x16x32_f16(wreg[of][ks], bf,      \
                                                           acc[of][mf], 0, 0, 0); \
  }                                                                               \
  __builtin_amdgcn_s_setprio(0);

// bias+relu+cvt, store acc frags into 32m x 256k tile (k-dim = this layer's o)
#define STORE_FRAG(DST)                                                           \
  _Pragma("unroll") for (int of = 0; of < 2; ++of)                                \
  _Pragma("unroll") for (int mf = 0; mf < 2; ++mf) {                              \
    f16x4 hv;                                                                     \
    _Pragma("unroll") for (int j = 0; j < 4; ++j)                                 \
        hv[j] = (f16)fmaxf(acc[of][mf][j] + biasv[of][j], 0.f);                   \
    *(f16x4*)((DST) + (wg * 2 + mf) * 1024 + (of * 2 + (g >> 1)) * 256 +          \
              r * 16 + (g & 1) * 8) = hv;                                         \
  }

#define POOLUP                                                                    \
  _Pragma("unroll") for (int of = 0; of < 2; ++of)                                \
  _Pragma("unroll") for (int mf = 0; mf < 2; ++mf)                                \
  _Pragma("unroll") for (int j = 0; j < 4; ++j) {                                 \
    f16 hv = (f16)fmaxf(acc[of][mf][j] + biasv[of][j], 0.f);                      \
    if (hv > pool[of][mf][j]) pool[of][mf][j] = hv;                               \
  }

// all 16 waves: wave w produces y1 frag (ks=w>>1, mf=w&1) for row NN
#define PRODUCE_Y1(NN, DST)                                                       \
  {                                                                               \
    float simv = sml[(NN) * 32 + mp * 16 + r];                                    \
    f16x8 c8 = *(const f16x8*)(c1h + (NN) * 264 + kp * 32 + g * 8);               \
    f16x8 h;                                                                      \
    _Pragma("unroll") for (int q = 0; q < 4; ++q) {                               \
      h[q] = (f16)fmaxf(fmaf(w1a[q], simv, (float)c8[q]), 0.f);                   \
      h[4 + q] = (f16)fmaxf(fmaf(w1b[q], simv, (float)c8[4 + q]), 0.f);           \
    }                                                                             \
    *(f16x8*)((DST) + w * 1024 + lane * 16) = h;                                  \
  }

// 16 waves: A=0-7 (L2/L4), B=8-15 (L3+pool/L5). o-split 32/wave -> wreg 64 VGPR.
__global__ __launch_bounds__(1024, 4) void k_mega(
    const float* __restrict__ sf, const float* __restrict__ tf,
    const float* __restrict__ seeds, const float* __restrict__ b1,
    const float* __restrict__ b2, const float* __restrict__ b3,
    const float* __restrict__ b4, const float* __restrict__ b5,
    const char* __restrict__ wsb, float* __restrict__ out) {
  const int mt = blockIdx.x, b = blockIdx.y, mb = mt * 32;
  const int tid = threadIdx.x;
  const int w = tid >> 6, lane = tid & 63, g = lane >> 4, r = lane & 15;
  const int grp = w >> 3, wg = w & 7;
  const int kp = w >> 1, mp = w & 1;

  const float* w14t = (const float*)(wsb + OFFB_W14T);
  const float* invt = (const float*)(wsb + OFFB_INVT) + b * 64;
  const float* invs = (const float*)(wsb + OFFB_INVS) + b * 256;
  const f16* w1h = (const f16*)(wsb + OFFB_W1H);
  const f16* w2h = (const f16*)(wsb + OFFB_W2H);
  const f16* w3h = (const f16*)(wsb + OFFB_W3H);
  const f16* w4h = (const f16*)(wsb + OFFB_W4H);
  const f16* w5h = (const f16*)(wsb + OFFB_W5H);

  __shared__ __align__(16) char yl[65536];   // y1 dbuf [0,32K) | y2 dbuf [32K,64K)
  __shared__ __align__(16) f16 c1h[64 * 264];
  __shared__ __align__(16) float sml[64 * 32];
#define Y1BUF(i) (yl + (i) * 16384)
#define Y2BUF(i) (yl + 32768 + (i) * 16384)

  // ---- stage raw t (64n x 256f, frag order) into yl[0..32K)
  {
    int n = tid & 63, fb = tid >> 6;
#pragma unroll
    for (int j = 0; j < 2; ++j) {
      int foct = j * 16 + fb;
      f16x8 h;
#pragma unroll
      for (int e = 0; e < 8; ++e)
        h[e] = (f16)tf[((size_t)b * FF + foct * 8 + e) * N1 + n];
      *(f16x8*)(yl + ((foct >> 2) * 4 + (n >> 4)) * 1024 +
                ((foct & 3) * 16 + (n & 15)) * 16) = h;
    }
  }
  // ---- stage s_norm (32m x 256f, frag order) into y2 buf0
  {
    int m = tid & 31, foct = tid >> 5;
    float iv = invs[mb + m];
    f16x8 h;
#pragma unroll
    for (int e = 0; e < 8; ++e)
      h[e] = (f16)(sf[((size_t)b * FF + foct * 8 + e) * N2 + mb + m] * iv);
    *(f16x8*)(yl + 32768 + ((foct >> 2) * 2 + (m >> 4)) * 1024 +
              ((foct & 3) * 16 + (m & 15)) * 16) = h;
  }
  __syncthreads();

  // ---- sim-GEMM (waves 0-7): D[n16][m16] = t^T s_norm, scale by invt -> sml
  if (w < 8) {
    const int nt = w >> 1, mfs = w & 1;
    f32x4 sa = {0.f, 0.f, 0.f, 0.f};
#pragma unroll
    for (int ks = 0; ks < 8; ++ks) {
      f16x8 af = *(const f16x8*)(yl + (ks * 4 + nt) * 1024 + lane * 16);
      f16x8 bfm = *(const f16x8*)(yl + 32768 + (ks * 2 + mfs) * 1024 + lane * 16);
      sa = __builtin_amdgcn_mfma_f32_16x16x32_f16(af, bfm, sa, 0, 0, 0);
    }
#pragma unroll
    for (int j = 0; j < 4; ++j) {
      int n = nt * 16 + g * 4 + j;
      sml[n * 32 + mfs * 16 + r] = sa[j] * invt[n];
    }
  }
  // ---- c1-GEMM (all 16 waves, o-split 16): c1[n][o] -> c1h f16
  {
    f16x8 w1f[8];
#pragma unroll
    for (int ks = 0; ks < 8; ++ks)
      w1f[ks] = *(const f16x8*)(w1h + (w * 16 + r) * 256 + ks * 32 + g * 8);
    f32x4 ac[4];
#pragma unroll
    for (int nf = 0; nf < 4; ++nf) ac[nf] = (f32x4){0.f, 0.f, 0.f, 0.f};
#pragma unroll
    for (int ks = 0; ks < 8; ++ks)
#pragma unroll
      for (int nf = 0; nf < 4; ++nf) {
        f16x8 bfm = *(const f16x8*)(yl + (ks * 4 + nf) * 1024 + lane * 16);
        ac[nf] = __builtin_amdgcn_mfma_f32_16x16x32_f16(w1f[ks], bfm, ac[nf], 0, 0, 0);
      }
    f32x4 b1v = *(const f32x4*)(b1 + w * 16 + g * 4);
    f32x4 wx = *(const f32x4*)(w14t + 256 + w * 16 + g * 4);
    f32x4 wy = *(const f32x4*)(w14t + 512 + w * 16 + g * 4);
    f32x4 wz = *(const f32x4*)(w14t + 768 + w * 16 + g * 4);
#pragma unroll
    for (int nf = 0; nf < 4; ++nf) {
      int n = nf * 16 + r;
      const float* sd = seeds + ((size_t)b * 64 + n) * 3;
      float sx = sd[0], sy = sd[1], sz = sd[2];
      f16x4 hv;
#pragma unroll
      for (int j = 0; j < 4; ++j)
        hv[j] = (f16)(ac[nf][j] + b1v[j] + wx[j] * sx + wy[j] * sy + wz[j] * sz);
      *(f16x4*)(c1h + n * 264 + w * 16 + g * 4) = hv;
    }
  }
  __syncthreads();   // sml, c1h published; all t/s reads done

  // ---- persistent registers (same names both groups)
  f16x8 wreg[2][8];
  f32x4 biasv[2];
  f16x4 pool[2][2];
  f32x4 acc[2][2];
  f32x4 w1a, w1b;
  {
    const f16* wsrc = grp ? w3h : w2h;
    const float* bsrc = grp ? b3 : b2;
#pragma unroll
    for (int of = 0; of < 2; ++of) {
#pragma unroll
      for (int ks = 0; ks < 8; ++ks)
        wreg[of][ks] = *(const f16x8*)(wsrc + (wg * 32 + of * 16 + r) * 256 +
                                       ks * 32 + g * 8);
      biasv[of] = *(const f32x4*)(bsrc + wg * 32 + of * 16 + g * 4);
    }
    w1a = *(const f32x4*)(w14t + kp * 32 + g * 8);
    w1b = *(const f32x4*)(w14t + kp * 32 + g * 8 + 4);
  }
#pragma unroll
  for (int of = 0; of < 2; ++of)
#pragma unroll
    for (int mf = 0; mf < 2; ++mf) pool[of][mf] = (f16x4){0, 0, 0, 0};

  PRODUCE_Y1(0, Y1BUF(0));   // overwrites t frags 0-15 (reads done)
  __syncthreads();

  // ---- main loop: A: L2(n)->y2[n&1]; B: L3(n-1)+pool; all: produce y1[n+1]
  for (int n = 0; n < N1; ++n) {
    if (grp == 0) {
      ZERO_ACC;
      GEMM2(Y1BUF(n & 1));
      STORE_FRAG(Y2BUF(n & 1));
    } else if (n > 0) {
      ZERO_ACC;
      GEMM2(Y2BUF((n - 1) & 1));
      POOLUP;
    }
    if (n + 1 < N1) PRODUCE_Y1(n + 1, Y1BUF((n + 1) & 1));
    __syncthreads();
  }

  // ---- tail: B finishes L3(63) + writes pooled tile; A loads W4
  if (grp == 1) {
    ZERO_ACC;
    GEMM2(Y2BUF(1));
    POOLUP;
#pragma unroll
    for (int of = 0; of < 2; ++of)
#pragma unroll
      for (int mf = 0; mf < 2; ++mf)
        *(f16x4*)(Y1BUF(0) + (wg * 2 + mf) * 1024 + (of * 2 + (g >> 1)) * 256 +
                  r * 16 + (g & 1) * 8) = pool[of][mf];
  } else {
#pragma unroll
    for (int of = 0; of < 2; ++of) {
#pragma unroll
      for (int ks = 0; ks < 8; ++ks)
        wreg[of][ks] = *(const f16x8*)(w4h + (wg * 32 + of * 16 + r) * 256 +
                                       ks * 32 + g * 8);
      biasv[of] = *(const f32x4*)(b4 + wg * 32 + of * 16 + g * 4);
    }
  }
  __syncthreads();
  // ---- L4 (A); B loads W5
  if (grp == 0) {
    ZERO_ACC;
    GEMM2(Y1BUF(0));
    STORE_FRAG(Y2BUF(0));
  } else {
#pragma unroll
    for (int of = 0; of < 2; ++of) {
#pragma unroll
      for (int ks = 0; ks < 8; ++ks)
        wreg[of][ks] = *(const f16x8*)(w5h + (wg * 32 + of * 16 + r) * 256 +
                                       ks * 32 + g * 8);
      biasv[of] = *(const f32x4*)(b5 + wg * 32 + of * 16 + g * 4);
    }
  }
  __syncthreads();
  // ---- L5 (B, no relu) -> out
  if (grp == 1) {
    ZERO_ACC;
    GEMM2(Y2BUF(0));
#pragma unroll
    for (int of = 0; of < 2; ++of)
#pragma unroll
      for (int mf = 0; mf < 2; ++mf) {
        float* op = out + ((size_t)(b * 256 + wg * 32 + of * 16 + g * 4)) * 256 +
                    mb + mf * 16 + r;
#pragma unroll
        for (int j = 0; j < 4; ++j)
          op[(size_t)j * 256] = acc[of][mf][j] + biasv[of][j];
      }
  }
}

extern "C" void kernel_launch(void* const* d_in, const int* in_sizes, int n_in,
                              void* d_out, int out_size, void* d_ws, size_t ws_size,
                              hipStream_t stream) {
  const float* sf = (const float*)d_in[0];
  const float* tf = (const float*)d_in[1];
  const float* seeds = (const float*)d_in[2];
  const float* W1 = (const float*)d_in[3];
  const float* b1 = (const float*)d_in[4];
  const float* W2 = (const float*)d_in[5];
  const float* b2 = (const float*)d_in[6];
  const float* W3 = (const float*)d_in[7];
  const float* b3 = (const float*)d_in[8];
  const float* W4 = (const float*)d_in[9];
  const float* b4 = (const float*)d_in[10];
  const float* W5 = (const float*)d_in[11];
  const float* b5 = (const float*)d_in[12];
  char* wsb = (char*)d_ws;
  float* out = (float*)d_out;

  k_prep<<<dim3(256, 6), 256, 0, stream>>>(W1, W2, W3, W4, W5, wsb);
  k_norms<<<dim3(BB), 256, 0, stream>>>(sf, tf, wsb);
  k_mega<<<dim3(8, BB), 1024, 0, stream>>>(sf, tf, seeds, b1, b2, b3, b4, b5,
                                           wsb, out);
}